// Round 1
// baseline (328.846 us; speedup 1.0000x reference)
//
#include <hip/hip_runtime.h>
#include <hip/hip_bf16.h>

typedef __attribute__((ext_vector_type(4))) float floatx4;
typedef __attribute__((ext_vector_type(8))) short shortx8;
typedef __attribute__((ext_vector_type(4))) short shortx4;

#define MFMA_BF16(A,B,C) __builtin_amdgcn_mfma_f32_16x16x32_bf16((A),(B),(C),0,0,0)
#define NEG_INF (-__builtin_inff())

static __device__ __forceinline__ unsigned short f2b(float f) {
    union { float f; unsigned u; } v; v.f = f;
    unsigned r = v.u + 0x7FFFu + ((v.u >> 16) & 1u);   // RNE fp32 -> bf16
    return (unsigned short)(r >> 16);
}
static __device__ __forceinline__ float EXP2F(float x) { return __builtin_amdgcn_exp2f(x); }

// ---------------- weights: transpose + bf16 ----------------
__global__ __launch_bounds__(256) void wtrans_kernel(
    const float* __restrict__ wq, const float* __restrict__ wk,
    const float* __restrict__ wv, const float* __restrict__ wo,
    unsigned short* __restrict__ wqt, unsigned short* __restrict__ wkt,
    unsigned short* __restrict__ wvt, unsigned short* __restrict__ wot)
{
    int gid = blockIdx.x * 256 + threadIdx.x;        // 640 blocks -> 163840 elems
    if (gid < 65536) {
        int n = gid >> 8, k = gid & 255;
        wqt[gid] = f2b(wq[k * 256 + n]);
    } else if (gid < 81920) {
        int j = gid - 65536, n = j >> 6, k = j & 63;
        wkt[j] = f2b(wk[k * 256 + n]);
    } else if (gid < 98304) {
        int j = gid - 81920, n = j >> 6, k = j & 63;
        wvt[j] = f2b(wv[k * 256 + n]);
    } else {
        int j = gid - 98304, n = j >> 8, k = j & 255;
        wot[j] = f2b(wo[k * 256 + n]);
    }
}

// ---------------- q projection + RoPE + scale ----------------
__global__ __launch_bounds__(256) void qproj_kernel(
    const float* __restrict__ query, const unsigned short* __restrict__ wqt,
    const float* __restrict__ bq, const float* __restrict__ cosb,
    const float* __restrict__ sinb, unsigned short* __restrict__ qr)
{
    const int tid = threadIdx.x;
    const int wave = tid >> 6, lane = tid & 63;
    const int c = lane & 15, quad = lane >> 4;
    const int m0 = blockIdx.x * 64;

    shortx8 aA[8];
    {
        const int mrow = m0 + wave * 16 + c;
        #pragma unroll
        for (int ks = 0; ks < 8; ks++) {
            const float* p = query + mrow * 256 + ks * 32 + quad * 8;
            floatx4 f0 = *(const floatx4*)p;
            floatx4 f1 = *(const floatx4*)(p + 4);
            shortx8 a;
            #pragma unroll
            for (int j = 0; j < 4; j++) { a[j] = (short)f2b(f0[j]); a[j + 4] = (short)f2b(f1[j]); }
            aA[ks] = a;
        }
    }
    floatx4 acc[16];
    #pragma unroll
    for (int nt = 0; nt < 16; nt++) { acc[nt][0]=0.f; acc[nt][1]=0.f; acc[nt][2]=0.f; acc[nt][3]=0.f; }
    #pragma unroll
    for (int nt = 0; nt < 16; nt++) {
        #pragma unroll
        for (int ks = 0; ks < 8; ks++) {
            shortx8 b = *(const shortx8*)(wqt + (nt * 16 + c) * 256 + ks * 32 + quad * 8);
            acc[nt] = MFMA_BF16(aA[ks], b, acc[nt]);
        }
    }
    const float sc = 0.09016844005556021f;  // (1/16) * log2(e)
    #pragma unroll
    for (int nt = 0; nt < 16; nt++) {
        const int col = nt * 16 + c;
        #pragma unroll
        for (int r = 0; r < 4; r++) {
            const int row = m0 + wave * 16 + quad * 4 + r;
            float v = acc[nt][r] + bq[col];
            float partner = __shfl_xor(v, 1);
            float cv = cosb[row * 256 + col];
            float sn = sinb[row * 256 + col];
            float rot = (col & 1) ? partner : -partner;
            qr[row * 256 + col] = f2b((v * cv + rot * sn) * sc);
        }
    }
}

// ---------------- k projection + partial RoPE ----------------
__global__ __launch_bounds__(256) void kproj_kernel(
    const float* __restrict__ key, const unsigned short* __restrict__ wkt,
    const float* __restrict__ bk, const float* __restrict__ cosb,
    const float* __restrict__ sinb, const int* __restrict__ nk,
    unsigned short* __restrict__ krw)
{
    const int tid = threadIdx.x;
    const int wave = tid >> 6, lane = tid & 63;
    const int c = lane & 15, quad = lane >> 4;
    const int m0 = blockIdx.x * 64;
    const int n_rot = 16448 - nk[0];
    int rep = n_rot / 4096; if (rep < 1) rep = 1;

    shortx8 aA[2];
    {
        const int mrow = m0 + wave * 16 + c;
        #pragma unroll
        for (int ks = 0; ks < 2; ks++) {
            const float* p = key + mrow * 64 + ks * 32 + quad * 8;
            floatx4 f0 = *(const floatx4*)p;
            floatx4 f1 = *(const floatx4*)(p + 4);
            shortx8 a;
            #pragma unroll
            for (int j = 0; j < 4; j++) { a[j] = (short)f2b(f0[j]); a[j + 4] = (short)f2b(f1[j]); }
            aA[ks] = a;
        }
    }
    floatx4 acc[16];
    #pragma unroll
    for (int nt = 0; nt < 16; nt++) { acc[nt][0]=0.f; acc[nt][1]=0.f; acc[nt][2]=0.f; acc[nt][3]=0.f; }
    #pragma unroll
    for (int nt = 0; nt < 16; nt++) {
        #pragma unroll
        for (int ks = 0; ks < 2; ks++) {
            shortx8 b = *(const shortx8*)(wkt + (nt * 16 + c) * 64 + ks * 32 + quad * 8);
            acc[nt] = MFMA_BF16(aA[ks], b, acc[nt]);
        }
    }
    #pragma unroll
    for (int nt = 0; nt < 16; nt++) {
        const int col = nt * 16 + c;
        #pragma unroll
        for (int r = 0; r < 4; r++) {
            const int row = m0 + wave * 16 + quad * 4 + r;
            float v = acc[nt][r] + bk[col];
            float partner = __shfl_xor(v, 1);
            float outv = v;
            if (row < n_rot) {
                int rc = row / rep;
                float cv = cosb[rc * 256 + col];
                float sn = sinb[rc * 256 + col];
                float rot = (col & 1) ? partner : -partner;
                outv = v * cv + rot * sn;
            }
            krw[row * 256 + col] = f2b(outv);
        }
    }
}

// ---------------- v projection, store transposed vt[d][kv] ----------------
__global__ __launch_bounds__(256) void vproj_kernel(
    const float* __restrict__ value, const unsigned short* __restrict__ wvt,
    const float* __restrict__ bv, unsigned short* __restrict__ vtg)
{
    __shared__ unsigned short tbuf[256 * 72];   // 36.9 KB, padded stride 72
    const int tid = threadIdx.x;
    const int wave = tid >> 6, lane = tid & 63;
    const int c = lane & 15, quad = lane >> 4;
    const int m0 = blockIdx.x * 64;

    shortx8 aA[2];
    {
        const int mrow = m0 + wave * 16 + c;
        #pragma unroll
        for (int ks = 0; ks < 2; ks++) {
            const float* p = value + mrow * 64 + ks * 32 + quad * 8;
            floatx4 f0 = *(const floatx4*)p;
            floatx4 f1 = *(const floatx4*)(p + 4);
            shortx8 a;
            #pragma unroll
            for (int j = 0; j < 4; j++) { a[j] = (short)f2b(f0[j]); a[j + 4] = (short)f2b(f1[j]); }
            aA[ks] = a;
        }
    }
    floatx4 acc[16];
    #pragma unroll
    for (int nt = 0; nt < 16; nt++) { acc[nt][0]=0.f; acc[nt][1]=0.f; acc[nt][2]=0.f; acc[nt][3]=0.f; }
    #pragma unroll
    for (int nt = 0; nt < 16; nt++) {
        #pragma unroll
        for (int ks = 0; ks < 2; ks++) {
            shortx8 b = *(const shortx8*)(wvt + (nt * 16 + c) * 64 + ks * 32 + quad * 8);
            acc[nt] = MFMA_BF16(aA[ks], b, acc[nt]);
        }
    }
    #pragma unroll
    for (int nt = 0; nt < 16; nt++) {
        const int col = nt * 16 + c;
        #pragma unroll
        for (int r = 0; r < 4; r++) {
            const int rl = wave * 16 + quad * 4 + r;
            tbuf[col * 72 + rl] = f2b(acc[nt][r] + bv[col]);
        }
    }
    __syncthreads();
    #pragma unroll
    for (int i = 0; i < 8; i++) {
        int G = i * 256 + tid;          // 2048 16B granules
        int n = G >> 3, g = G & 7;
        *(floatx4*)(vtg + n * 16448 + m0 + g * 8) = *(const floatx4*)(tbuf + n * 72 + g * 8);
    }
}

// ---------------- flash attention, 8 KV splits ----------------
__global__ __launch_bounds__(512, 2) void flash_kernel(
    const unsigned short* __restrict__ qr, const unsigned short* __restrict__ kr,
    const unsigned short* __restrict__ vt, float* __restrict__ Opart,
    float* __restrict__ Mpart, float* __restrict__ Lpart)
{
    __shared__ unsigned short smem[32768];   // exactly 64 KB
    unsigned short* kbuf = smem;             // 64 x 256, XOR-swizzled granules
    unsigned short* vbuf = smem + 16384;     // 256 x 64, XOR-swizzled granules
    unsigned short* pbuf = smem;             // aliases kbuf (guarded by barrier)

    const int tid = threadIdx.x;
    const int wave = tid >> 6, lane = tid & 63;
    const int c = lane & 15, quad = lane >> 4;
    const int cx = c & 7;
    const int qrow0 = blockIdx.x * 128 + wave * 16;
    const int s = blockIdx.y;
    const int t0 = (s * 257) / 8, t1 = ((s + 1) * 257) / 8;

    shortx8 aQ[8];
    #pragma unroll
    for (int ks = 0; ks < 8; ks++)
        aQ[ks] = *(const shortx8*)(qr + (qrow0 + c) * 256 + ks * 32 + quad * 8);

    floatx4 o[16];
    #pragma unroll
    for (int nt = 0; nt < 16; nt++) { o[nt][0]=0.f; o[nt][1]=0.f; o[nt][2]=0.f; o[nt][3]=0.f; }
    float m_i[4] = { NEG_INF, NEG_INF, NEG_INF, NEG_INF };
    float l_i[4] = { 0.f, 0.f, 0.f, 0.f };

    for (int t = t0; t < t1; t++) {
        const int kv0 = t * 64;
        #pragma unroll
        for (int i = 0; i < 4; i++) {   // K tile: 2048 granules, swizzle folded into source
            int L = i * 512 + tid;
            int kv = L >> 5, p = L & 31;
            int g = (p & 24) | ((p & 7) ^ (kv & 7));
            *(floatx4*)(kbuf + L * 8) = *(const floatx4*)(kr + (kv0 + kv) * 256 + g * 8);
        }
        #pragma unroll
        for (int i = 0; i < 4; i++) {   // Vt tile
            int L = i * 512 + tid;
            int d = L >> 3, p = L & 7;
            int g = p ^ (d & 7);
            *(floatx4*)(vbuf + L * 8) = *(const floatx4*)(vt + d * 16448 + kv0 + g * 8);
        }
        __syncthreads();

        floatx4 sv[4];
        #pragma unroll
        for (int nt = 0; nt < 4; nt++) { sv[nt][0]=0.f; sv[nt][1]=0.f; sv[nt][2]=0.f; sv[nt][3]=0.f; }
        #pragma unroll
        for (int nt = 0; nt < 4; nt++) {
            const unsigned short* krow = kbuf + (nt * 16 + c) * 256;
            #pragma unroll
            for (int ks = 0; ks < 8; ks++) {
                int p = ((ks >> 1) * 8) | ((((ks & 1) << 2) + quad) ^ cx);
                shortx8 b = *(const shortx8*)(krow + p * 8);
                sv[nt] = MFMA_BF16(aQ[ks], b, sv[nt]);
            }
        }
        // online softmax (log2-scaled logits)
        float alpha[4];
        #pragma unroll
        for (int r = 0; r < 4; r++) {
            float mx = fmaxf(fmaxf(sv[0][r], sv[1][r]), fmaxf(sv[2][r], sv[3][r]));
            #pragma unroll
            for (int off = 1; off < 16; off <<= 1) mx = fmaxf(mx, __shfl_xor(mx, off));
            float mn = fmaxf(m_i[r], mx);
            alpha[r] = EXP2F(m_i[r] - mn);
            m_i[r] = mn;
            float rs = 0.f;
            #pragma unroll
            for (int nt = 0; nt < 4; nt++) {
                float pv = EXP2F(sv[nt][r] - mn);
                sv[nt][r] = pv;
                rs += pv;
            }
            #pragma unroll
            for (int off = 1; off < 16; off <<= 1) rs += __shfl_xor(rs, off);
            l_i[r] = l_i[r] * alpha[r] + rs;
        }
        #pragma unroll
        for (int nt = 0; nt < 16; nt++) {
            o[nt][0] *= alpha[0]; o[nt][1] *= alpha[1];
            o[nt][2] *= alpha[2]; o[nt][3] *= alpha[3];
        }
        __syncthreads();   // all kbuf reads done -> safe to write P over it
        #pragma unroll
        for (int nt = 0; nt < 4; nt++) {
            #pragma unroll
            for (int r = 0; r < 4; r++)
                pbuf[wave * 1280 + (quad * 4 + r) * 80 + nt * 16 + c] = f2b(sv[nt][r]);
        }
        shortx8 aP0 = *(const shortx8*)(pbuf + wave * 1280 + c * 80 + quad * 8);
        shortx8 aP1 = *(const shortx8*)(pbuf + wave * 1280 + c * 80 + 32 + quad * 8);
        const int p0 = quad ^ cx;
        const int p1 = (quad + 4) ^ cx;
        #pragma unroll
        for (int nt = 0; nt < 16; nt++) {
            const unsigned short* vrow = vbuf + (nt * 16 + c) * 64;
            shortx8 b0 = *(const shortx8*)(vrow + p0 * 8);
            o[nt] = MFMA_BF16(aP0, b0, o[nt]);
            shortx8 b1 = *(const shortx8*)(vrow + p1 * 8);
            o[nt] = MFMA_BF16(aP1, b1, o[nt]);
        }
        __syncthreads();   // before next staging overwrites kbuf/vbuf
    }
    float* Ob = Opart + s * (4096 * 256);
    #pragma unroll
    for (int nt = 0; nt < 16; nt++) {
        #pragma unroll
        for (int r = 0; r < 4; r++)
            Ob[(qrow0 + quad * 4 + r) * 256 + nt * 16 + c] = o[nt][r];
    }
    if (c == 0) {
        #pragma unroll
        for (int r = 0; r < 4; r++) {
            Mpart[s * 4096 + qrow0 + quad * 4 + r] = m_i[r];
            Lpart[s * 4096 + qrow0 + quad * 4 + r] = l_i[r];
        }
    }
}

// ---------------- split combine + output projection ----------------
__global__ __launch_bounds__(256) void oproj_kernel(
    const float* __restrict__ Opart, const float* __restrict__ Mpart,
    const float* __restrict__ Lpart, const unsigned short* __restrict__ wot,
    const float* __restrict__ bo, float* __restrict__ outp)
{
    __shared__ float wts[64 * 8];
    __shared__ unsigned short xb[64 * 264];
    const int tid = threadIdx.x;
    const int wave = tid >> 6, lane = tid & 63;
    const int c = lane & 15, quad = lane >> 4;
    const int m0 = blockIdx.x * 64;

    if (tid < 64) {
        const int row = m0 + tid;
        float ms[8], mx = NEG_INF;
        #pragma unroll
        for (int sp = 0; sp < 8; sp++) { ms[sp] = Mpart[sp * 4096 + row]; mx = fmaxf(mx, ms[sp]); }
        float den = 0.f, w[8];
        #pragma unroll
        for (int sp = 0; sp < 8; sp++) {
            w[sp] = EXP2F(ms[sp] - mx);
            den += w[sp] * Lpart[sp * 4096 + row];
        }
        float inv = 1.0f / den;
        #pragma unroll
        for (int sp = 0; sp < 8; sp++) wts[tid * 8 + sp] = w[sp] * inv;
    }
    __syncthreads();
    for (int it = 0; it < 16; it++) {
        int rl = it * 4 + (tid >> 6);
        int ch = tid & 63;
        int row = m0 + rl;
        floatx4 acc; acc[0]=0.f; acc[1]=0.f; acc[2]=0.f; acc[3]=0.f;
        #pragma unroll
        for (int sp = 0; sp < 8; sp++) {
            floatx4 ov = *(const floatx4*)(Opart + sp * 1048576 + row * 256 + ch * 4);
            float w = wts[rl * 8 + sp];
            acc[0] += w * ov[0]; acc[1] += w * ov[1]; acc[2] += w * ov[2]; acc[3] += w * ov[3];
        }
        shortx4 xv;
        xv[0] = (short)f2b(acc[0]); xv[1] = (short)f2b(acc[1]);
        xv[2] = (short)f2b(acc[2]); xv[3] = (short)f2b(acc[3]);
        *(shortx4*)(xb + rl * 264 + ch * 4) = xv;
    }
    __syncthreads();
    shortx8 aX[8];
    #pragma unroll
    for (int ks = 0; ks < 8; ks++)
        aX[ks] = *(const shortx8*)(xb + (wave * 16 + c) * 264 + ks * 32 + quad * 8);
    floatx4 acc2[16];
    #pragma unroll
    for (int nt = 0; nt < 16; nt++) { acc2[nt][0]=0.f; acc2[nt][1]=0.f; acc2[nt][2]=0.f; acc2[nt][3]=0.f; }
    #pragma unroll
    for (int nt = 0; nt < 16; nt++) {
        #pragma unroll
        for (int ks = 0; ks < 8; ks++) {
            shortx8 b = *(const shortx8*)(wot + (nt * 16 + c) * 256 + ks * 32 + quad * 8);
            acc2[nt] = MFMA_BF16(aX[ks], b, acc2[nt]);
        }
    }
    #pragma unroll
    for (int nt = 0; nt < 16; nt++) {
        const int col = nt * 16 + c;
        #pragma unroll
        for (int r = 0; r < 4; r++) {
            const int row = m0 + wave * 16 + quad * 4 + r;
            outp[row * 256 + col] = acc2[nt][r] + bo[col];
        }
    }
}

extern "C" void kernel_launch(void* const* d_in, const int* in_sizes, int n_in,
                              void* d_out, int out_size, void* d_ws, size_t ws_size,
                              hipStream_t stream) {
    const float* query = (const float*)d_in[0];
    const float* key   = (const float*)d_in[1];
    const float* value = (const float*)d_in[2];
    const float* cosb  = (const float*)d_in[3];
    const float* sinb  = (const float*)d_in[4];
    const float* wq    = (const float*)d_in[5];
    const float* bq    = (const float*)d_in[6];
    const float* wk    = (const float*)d_in[7];
    const float* bk    = (const float*)d_in[8];
    const float* wv    = (const float*)d_in[9];
    const float* bv    = (const float*)d_in[10];
    const float* wo    = (const float*)d_in[11];
    const float* bo    = (const float*)d_in[12];
    const int*   nk    = (const int*)d_in[13];

    char* ws = (char*)d_ws;
    unsigned short* wqt = (unsigned short*)(ws + 0);          // 131072 B
    unsigned short* wkt = (unsigned short*)(ws + 131072);     // 32768 B
    unsigned short* wvt = (unsigned short*)(ws + 163840);     // 32768 B
    unsigned short* wot = (unsigned short*)(ws + 196608);     // 131072 B
    unsigned short* qr  = (unsigned short*)(ws + 327680);     // 2 MB
    unsigned short* krw = (unsigned short*)(ws + 2424832);    // 8.42 MB
    unsigned short* vtg = (unsigned short*)(ws + 10846208);   // 8.42 MB
    float* Opart = (float*)(ws + 19267584);                   // 32 MB (8 splits)
    float* Mpart = (float*)(ws + 52822016);                   // 128 KB
    float* Lpart = (float*)(ws + 52953088);                   // 128 KB
    float* outp  = (float*)d_out;

    wtrans_kernel<<<dim3(640), dim3(256), 0, stream>>>(wq, wk, wv, wo, wqt, wkt, wvt, wot);
    qproj_kernel<<<dim3(64), dim3(256), 0, stream>>>(query, wqt, bq, cosb, sinb, qr);
    kproj_kernel<<<dim3(257), dim3(256), 0, stream>>>(key, wkt, bk, cosb, sinb, nk, krw);
    vproj_kernel<<<dim3(257), dim3(256), 0, stream>>>(value, wvt, bv, vtg);
    flash_kernel<<<dim3(32, 8), dim3(512), 0, stream>>>(qr, krw, vtg, Opart, Mpart, Lpart);
    oproj_kernel<<<dim3(64), dim3(256), 0, stream>>>(Opart, Mpart, Lpart, wot, bo, outp);
}